// Round 14
// baseline (45.909 us; speedup 1.0000x reference)
//
#include <hip/hip_runtime.h>
#include <hip/hip_bf16.h>

// DLRM-like, round 14: wave-specialized megakernel. SPB=64, 512 thr, 1 blk/CU.
// Waves 0-3: MLP chain (per-wave weight staging, own vmcnt, no loop barriers).
// Waves 4-7: gather+gram (16 samples each, 2-deep, chunked 2/10/4 between the
// three block syncs). Each SIMD = 1 MLP wave + 1 gather wave -> stalls overlap.
//
// LDS: [0,65536) X1[64][512] XOR  (AsDense[64][64] aliases after sync2)
//      [65536,98304) X2[64][256] XOR (top staging bufs alias after sync3)
//      [98304,143360) AsGram[64][352] XOR
//      [143360,159744) per-wave weight staging bufs
//
// ws layout (bytes): W0t 512x32 @0 | W1t 256x512 @32768 | W2t 64x256 @294912
//                    Wtt 256x416 @327680 (k>=389 zero)

#define BATCH   16384
#define NSPARSE 26
#define VOCAB   100000
#define KTOP    416
#define KREAL   389
#define SPB     64

#define WAIT_VMCNT(N) asm volatile("s_waitcnt vmcnt(" #N ")" ::: "memory")
#define WAIT_LGKM0()  asm volatile("s_waitcnt lgkmcnt(0)" ::: "memory")
#define SBAR0() __builtin_amdgcn_sched_barrier(0)

typedef __attribute__((ext_vector_type(8)))  short bf16x8;
typedef __attribute__((ext_vector_type(4)))  short s16x4;
typedef __attribute__((ext_vector_type(4)))  float f32x4;
typedef __attribute__((ext_vector_type(16))) float f32x16;

__device__ inline void gload_lds16(const void* g, void* l) {
    __builtin_amdgcn_global_load_lds(
        (const __attribute__((address_space(1))) void*)g,
        (__attribute__((address_space(3))) void*)l, 16, 0, 0);
}

__device__ inline short f2bf(float x) {
    __hip_bfloat16 h = __float2bfloat16(x);
    return *reinterpret_cast<short*>(&h);
}

__device__ inline f32x4 mfma16(bf16x8 a, bf16x8 b, f32x4 c) {
    return __builtin_amdgcn_mfma_f32_16x16x32_bf16(a, b, c, 0, 0, 0);
}

// XOR-swizzled LDS addressing (row-major [*][ld] bf16, byte ^= (row&7)<<4)
__device__ inline short* ldsx2(char* base, int row, int ld, int col) {
    int byte = ((row * ld + col) * 2) ^ ((row & 7) << 4);
    return (short*)(base + byte);
}
__device__ inline bf16x8 ldsx16(const char* base, int row, int ld, int col) {
    int byte = ((row * ld + col) * 2) ^ ((row & 7) << 4);
    return *(const bf16x8*)(base + byte);
}

// ------------------------------------------------- prep: tiled transpose ----
__global__ __launch_bounds__(256)
void prep_weights(const float* __restrict__ W0, const float* __restrict__ W1,
                  const float* __restrict__ W2, const float* __restrict__ Wt,
                  short* __restrict__ W0t, short* __restrict__ W1t,
                  short* __restrict__ W2t, short* __restrict__ Wtt)
{
    __shared__ float tile[32][36];
    int b = blockIdx.x, t = threadIdx.x;
    const float* src; short* dst; int K, N, Kpad, k0, n0;
    if (b < 16)        {              src = W0; dst = W0t; K = 13;  N = 512; Kpad = 32;  k0 = 0;           n0 = b * 32; }
    else if (b < 144)  { int i = b - 16;  src = W1; dst = W1t; K = 512; N = 256; Kpad = 512; k0 = (i >> 3) * 32; n0 = (i & 7) * 32; }
    else if (b < 160)  { int i = b - 144; src = W2; dst = W2t; K = 256; N = 64;  Kpad = 256; k0 = (i >> 1) * 32; n0 = (i & 1) * 32; }
    else               { int i = b - 160; src = Wt; dst = Wtt; K = 389; N = 256; Kpad = 416; k0 = (i >> 3) * 32; n0 = (i & 7) * 32; }

    int r = t >> 3, c4 = (t & 7) * 4;
    int gr = k0 + r;
    float4 v = make_float4(0.f, 0.f, 0.f, 0.f);
    if (gr < K) v = *(const float4*)(src + (size_t)gr * N + n0 + c4);
    tile[r][c4 + 0] = v.x; tile[r][c4 + 1] = v.y;
    tile[r][c4 + 2] = v.z; tile[r][c4 + 3] = v.w;
    __syncthreads();
    s16x4 o;
    #pragma unroll
    for (int j = 0; j < 4; ++j) o[j] = f2bf(tile[c4 + j][r]);
    *(s16x4*)&dst[(size_t)(n0 + r) * Kpad + k0 + c4] = o;
}

// ------------------------------------------------------ gram chunk (wave) ----
template<int CNT>
__device__ void gram_run(int s0, int gw, int sbase,
                         const int* __restrict__ sparse,
                         const float* __restrict__ tables,
                         char* AsG, int lane)
{
    int row = lane & 31, half = lane >> 5;
    int srow = (row < NSPARSE) ? row : 0;   // lanes>=26 dup row 0; garbage
    int sl0 = gw * 16 + s0;                 // lands only in gram r,c>=26

    const float* rp0 = tables + ((long)srow * VOCAB +
        sparse[(sbase + sl0) * NSPARSE + srow]) * 64 + half * 8;
    f32x4 Ca[4], Cb[4], Na[4], Nb[4];
    #pragma unroll
    for (int t = 0; t < 4; ++t) {
        Ca[t] = *(const f32x4*)(rp0 + t * 16);
        Cb[t] = *(const f32x4*)(rp0 + t * 16 + 4);
    }
    #pragma unroll
    for (int li = 0; li < CNT; ++li) {
        if (li + 1 < CNT) {
            const float* rp = tables + ((long)srow * VOCAB +
                sparse[(sbase + sl0 + li + 1) * NSPARSE + srow]) * 64 + half * 8;
            #pragma unroll
            for (int t = 0; t < 4; ++t) {
                Na[t] = *(const f32x4*)(rp + t * 16);
                Nb[t] = *(const f32x4*)(rp + t * 16 + 4);
            }
        }
        f32x16 acc = {};
        #pragma unroll
        for (int t = 0; t < 4; ++t) {
            bf16x8 f;
            #pragma unroll
            for (int j = 0; j < 4; ++j) f[j] = f2bf(Ca[t][j]);
            #pragma unroll
            for (int j = 0; j < 4; ++j) f[4 + j] = f2bf(Cb[t][j]);
            acc = __builtin_amdgcn_mfma_f32_32x32x16_bf16(f, f, acc, 0, 0, 0);
        }
        int c = row, sl = sl0 + li;
        if (c < NSPARSE) {
            #pragma unroll
            for (int reg = 0; reg < 16; ++reg) {
                int r = (reg & 3) + 8 * (reg >> 2) + 4 * half;
                if (r < c) {
                    int p = r * (2 * NSPARSE - r - 1) / 2 + (c - r - 1);
                    int byte = ((sl * 352 + p) * 2) ^ ((sl & 7) << 4);
                    *(short*)(AsG + byte) = f2bf(acc[reg]);
                }
            }
        }
        #pragma unroll
        for (int t = 0; t < 4; ++t) { Ca[t] = Na[t]; Cb[t] = Nb[t]; }
    }
}

// ------------------------------------------------------------ megakernel ----
__global__ __launch_bounds__(512, 1)
void fused_all(const int* __restrict__ sparse, const float* __restrict__ tables,
               const float* __restrict__ D,
               const short* __restrict__ W0t, const float* __restrict__ b0,
               const short* __restrict__ W1t, const float* __restrict__ b1,
               const short* __restrict__ W2t, const float* __restrict__ b2,
               const short* __restrict__ Wtt, const float* __restrict__ bt,
               float* __restrict__ out)
{
    __shared__ __align__(16) char smem[159744];
    char* X1s  = smem;             // [64][512] XOR
    char* AsD  = smem;             // [64][64]  XOR (aliases X1s after sync2)
    char* X2s  = smem + 65536;     // [64][256] XOR (top bufs alias after sync3)
    char* AsG  = smem + 98304;     // [64][352] XOR
    char* wbuf = smem + 143360;    // per-wave staging

    int tid = threadIdx.x;
    int w = tid >> 6, lane = tid & 63;
    int lr = lane & 15, lg = lane >> 4;
    int swz8 = (lg ^ (lr & 3)) * 8;
    int sbase = blockIdx.x * SPB;
    bool mlp = (w < 4);

    // ============ section 1: p0 (MLP waves) || gram 0..1 + pads (gather) ====
    if (mlp) {
        bf16x8 a[4];
        #pragma unroll
        for (int mi = 0; mi < 4; ++mi) {
            bf16x8 t = {};
            if (lg < 2) {
                #pragma unroll
                for (int j = 0; j < 8; ++j) {
                    int k = lg * 8 + j;
                    if (k < 13)
                        t[j] = f2bf(D[(size_t)(sbase + mi * 16 + lr) * 13 + k]);
                }
            }
            a[mi] = t;
        }
        f32x4 acc[4][8] = {};
        #pragma unroll
        for (int ni = 0; ni < 8; ++ni) {
            int n = w * 128 + ni * 16 + lr;
            bf16x8 b = *(const bf16x8*)(W0t + (size_t)n * 32 + lg * 8);
            #pragma unroll
            for (int mi = 0; mi < 4; ++mi)
                acc[mi][ni] = mfma16(a[mi], b, acc[mi][ni]);
        }
        #pragma unroll
        for (int ni = 0; ni < 8; ++ni) {
            int col = w * 128 + ni * 16 + lr;
            float bv = b0[col];
            #pragma unroll
            for (int mi = 0; mi < 4; ++mi)
                #pragma unroll
                for (int j = 0; j < 4; ++j)
                    *ldsx2(X1s, mi * 16 + lg * 4 + j, 512, col) =
                        f2bf(fmaxf(acc[mi][ni][j] + bv, 0.f));
        }
    } else {
        gram_run<2>(0, w - 4, sbase, sparse, tables, AsG, lane);
        for (int x = lane; x < 16 * 27; x += 64) {   // zero pad cols 325..351
            int sl = (w - 4) * 16 + x / 27, c = 325 + x % 27;
            int byte = ((sl * 352 + c) * 2) ^ ((sl & 7) << 4);
            *(short*)(AsG + byte) = 0;
        }
    }
    __syncthreads();   // X1s ready

    // ============ section 2: p1 (MLP) || gram 2..11 (gather) ================
    if (mlp) {
        char* buf = wbuf + w * 4096;
        f32x4 acc[4][4] = {};
        for (int k = 0; k < 16; ++k) {
            int k0 = k * 32;
            #pragma unroll
            for (int it = 0; it < 4; ++it) {
                int slot = it * 64 + lane;
                int n = slot >> 2, kc = slot & 3;
                gload_lds16(W1t + (size_t)(w * 64 + n) * 512 + k0 + (kc ^ (n & 3)) * 8,
                            buf + slot * 16);
            }
            WAIT_VMCNT(0); SBAR0();
            bf16x8 a[4];
            #pragma unroll
            for (int mi = 0; mi < 4; ++mi)
                a[mi] = ldsx16(X1s, mi * 16 + lr, 512, k0 + lg * 8);
            #pragma unroll
            for (int ni = 0; ni < 4; ++ni) {
                bf16x8 b = *(const bf16x8*)(buf + ((ni * 16 + lr) * 32 + swz8) * 2);
                #pragma unroll
                for (int mi = 0; mi < 4; ++mi)
                    acc[mi][ni] = mfma16(a[mi], b, acc[mi][ni]);
            }
            WAIT_LGKM0(); SBAR0();   // reads done before next overwrite
        }
        #pragma unroll
        for (int ni = 0; ni < 4; ++ni) {
            int col = w * 64 + ni * 16 + lr;
            float bv = b1[col];
            #pragma unroll
            for (int mi = 0; mi < 4; ++mi)
                #pragma unroll
                for (int j = 0; j < 4; ++j)
                    *ldsx2(X2s, mi * 16 + lg * 4 + j, 256, col) =
                        f2bf(fmaxf(acc[mi][ni][j] + bv, 0.f));
        }
    } else {
        gram_run<10>(2, w - 4, sbase, sparse, tables, AsG, lane);
    }
    __syncthreads();   // X2s ready; X1s dead -> AsD region usable

    // ============ section 3: p2 (MLP) || gram 12..15 (gather) ===============
    if (mlp) {
        char* buf = wbuf + w * 4096;
        f32x4 acc[4] = {};
        for (int k = 0; k < 8; ++k) {
            int k0 = k * 32;
            {
                int n = lane >> 2, kc = lane & 3;
                gload_lds16(W2t + (size_t)(w * 16 + n) * 256 + k0 + (kc ^ (n & 3)) * 8,
                            buf + lane * 16);
            }
            WAIT_VMCNT(0); SBAR0();
            bf16x8 b = *(const bf16x8*)(buf + (lr * 32 + swz8) * 2);
            #pragma unroll
            for (int mi = 0; mi < 4; ++mi) {
                bf16x8 a = ldsx16(X2s, mi * 16 + lr, 256, k0 + lg * 8);
                acc[mi] = mfma16(a, b, acc[mi]);
            }
            WAIT_LGKM0(); SBAR0();
        }
        int col = w * 16 + lr;
        float bv = b2[col];
        #pragma unroll
        for (int mi = 0; mi < 4; ++mi)
            #pragma unroll
            for (int j = 0; j < 4; ++j)
                *ldsx2(AsD, mi * 16 + lg * 4 + j, 64, col) =
                    f2bf(fmaxf(acc[mi][j] + bv, 0.f));
    } else {
        gram_run<4>(12, w - 4, sbase, sparse, tables, AsG, lane);
    }
    __syncthreads();   // As complete; X2s dead -> top bufs

    // ============ top GEMM: all 8 waves, N=32/wave, 2-deep counted ==========
    {
        char* bufA = X2s + w * 4096;
        char* bufB = bufA + 2048;
        auto stg = [&](char* dst, int k0) {
            #pragma unroll
            for (int it = 0; it < 2; ++it) {
                int slot = it * 64 + lane;
                int n = slot >> 2, kc = slot & 3;
                gload_lds16(Wtt + (size_t)(w * 32 + n) * 416 + k0 + (kc ^ (n & 3)) * 8,
                            dst + slot * 16);
            }
        };
        stg(bufA, 0);
        stg(bufB, 32);
        f32x4 acc[4][2] = {};
        for (int k = 0; k < 13; ++k) {
            if (k < 11) { WAIT_VMCNT(2); } else { WAIT_VMCNT(0); }
            SBAR0();
            int k0 = k * 32;
            char* buf = (k & 1) ? bufB : bufA;
            bf16x8 a[4];
            #pragma unroll
            for (int mi = 0; mi < 4; ++mi) {
                int r = mi * 16 + lr;
                a[mi] = (k0 < 64) ? ldsx16(AsD, r, 64, k0 + lg * 8)
                                  : ldsx16(AsG, r, 352, k0 - 64 + lg * 8);
            }
            #pragma unroll
            for (int ni = 0; ni < 2; ++ni) {
                bf16x8 b = *(const bf16x8*)(buf + ((ni * 16 + lr) * 32 + swz8) * 2);
                #pragma unroll
                for (int mi = 0; mi < 4; ++mi)
                    acc[mi][ni] = mfma16(a[mi], b, acc[mi][ni]);
            }
            WAIT_LGKM0(); SBAR0();
            if (k + 2 < 13) stg(buf, (k + 2) * 32);
        }
        #pragma unroll
        for (int ni = 0; ni < 2; ++ni) {
            int col = w * 32 + ni * 16 + lr;
            float bv = bt[col];
            #pragma unroll
            for (int mi = 0; mi < 4; ++mi)
                #pragma unroll
                for (int j = 0; j < 4; ++j)
                    out[(size_t)(sbase + mi * 16 + lg * 4 + j) * 256 + col] =
                        acc[mi][ni][j] + bv;
        }
    }
}

// -------------------------------------------------------------- launch ----
extern "C" void kernel_launch(void* const* d_in, const int* in_sizes, int n_in,
                              void* d_out, int out_size, void* d_ws, size_t ws_size,
                              hipStream_t stream)
{
    const float* dense  = (const float*)d_in[0];
    const int*   sparse = (const int*)  d_in[1];
    const float* tables = (const float*)d_in[2];
    const float* W0     = (const float*)d_in[3];
    const float* b0     = (const float*)d_in[4];
    const float* W1     = (const float*)d_in[5];
    const float* b1     = (const float*)d_in[6];
    const float* W2     = (const float*)d_in[7];
    const float* b2     = (const float*)d_in[8];
    const float* Wt     = (const float*)d_in[9];
    const float* bt     = (const float*)d_in[10];
    float* out = (float*)d_out;

    char* ws = (char*)d_ws;
    short* W0t = (short*)(ws);
    short* W1t = (short*)(ws + 32768);
    short* W2t = (short*)(ws + 294912);
    short* Wtt = (short*)(ws + 327680);

    prep_weights<<<264, 256, 0, stream>>>(W0, W1, W2, Wt, W0t, W1t, W2t, Wtt);

    fused_all<<<BATCH / SPB, 512, 0, stream>>>(sparse, tables, dense,
                                               W0t, b0, W1t, b1, W2t, b2,
                                               Wtt, bt, out);
}